// Round 21
// baseline (806.746 us; speedup 1.0000x reference)
//
#include <hip/hip_runtime.h>
#include <math.h>

#define BTOT 1024
#define LEN  2048
#define T    100
#define HID  128
#define BPW  4

// time-embedding dim constants (f64 argument scaling, f32 sincos)
#define C1 0.025118864315095794
#define C2 6.309573444801933e-04
#define C3 1.5848931924611134e-05
#define C4 3.9810717055349735e-07

#define TEMB(td) \
  float d0 = sinf((float)(td)); \
  float d1 = cosf((float)((td) * C1)); \
  float d2 = sinf((float)((td) * C2)); \
  float d3 = cosf((float)((td) * C3)); \
  float d4 = sinf((float)((td) * C4));

__device__ __forceinline__ float sig(float x) { return 1.0f / (1.0f + expf(-x)); }

using v2f = __attribute__((ext_vector_type(2))) float;
__device__ __forceinline__ v2f mkv2(float a, float b) { v2f r; r.x = a; r.y = b; return r; }

template <int CTRL>
__device__ __forceinline__ float dppadd(float x) {
  int r = __builtin_amdgcn_update_dpp(0, __float_as_int(x), CTRL, 0xF, 0xF, false);
  return x + __int_as_float(r);
}
// shuffle-free 64-lane sum, result valid in lane 63 (validated round 20).
__device__ __forceinline__ float wred63(float x) {
  x = dppadd<0xB1>(x);    // quad_perm xor1
  x = dppadd<0x4E>(x);    // quad_perm xor2
  x = dppadd<0x124>(x);   // row_ror:4
  x = dppadd<0x128>(x);   // row_ror:8   -> all 16 lanes of each row = row sum
  x = dppadd<0x142>(x);   // ROW_BCAST15
  x = dppadd<0x143>(x);   // ROW_BCAST31 -> lane 63 = full sum
  return x;
}
// full 64-lane sum, ALL lanes valid (validated round 20).
__device__ __forceinline__ float wredall(float x) {
  x = dppadd<0xB1>(x);
  x = dppadd<0x4E>(x);
  x = dppadd<0x141>(x);
  x = dppadd<0x128>(x);
  x += __shfl_xor(x, 16);
  x += __shfl_xor(x, 32);
  return x;
}
// 4-lane quad sum (quad_perm only).
#define RED4(x) { x = dppadd<0xB1>(x); x = dppadd<0x4E>(x); }

// AGPR stash/read (validated r14). r18 lesson: VOP3P cannot read AGPRs on
// gfx950 -- weights round-trip through v_accvgpr_read.
#define AGSTASH(a_, v_) asm volatile("v_accvgpr_write_b32 %0, %1" : "=a"(a_) : "v"(v_))
#define AGREAD(v_, a_)  asm volatile("v_accvgpr_read_b32 %0, %1" : "=v"(v_) : "a"(a_))

// ---------------- Phase A: attention -- 8 waves/SIMD occupancy ----------------
// ROUND-21: attn measured ~5x above its VALU floor at 4 waves/SIMD ->
// latency-bound. 1024 blocks x 1024 threads (16 waves/block, 2 blocks/CU =
// 8 waves/SIMD, MAX occupancy), 4 events/thread (20 pinned VGPRs, fits the
// 64-arch cap). strip[16][T][8] = 51.2 KB; 54.4 KB/block x 2 <= 160 OK.
__global__ __attribute__((amdgpu_flat_work_group_size(1024, 1024)))
void attn_k(const float* __restrict__ ta1,
            const float* __restrict__ ta2,
            float* __restrict__ att) {
  const int b = blockIdx.x, tid = threadIdx.x;
  const int wave = tid >> 6, lane = tid & 63;

  __shared__ float qlds[T][8];
  __shared__ float strip[16][T][8];

  if (tid < T) {
    double ct = (double)(tid + 1) * 0.1;
    TEMB(ct);
    qlds[tid][0] = d0 * 0.35355339059327373f;  // fold 1/sqrt(8)
    qlds[tid][1] = d1 * 0.35355339059327373f;
    qlds[tid][2] = d2 * 0.35355339059327373f;
    qlds[tid][3] = d3 * 0.35355339059327373f;
    qlds[tid][4] = d4 * 0.35355339059327373f;
  }

#define E5(i) float e##i##_0, e##i##_1, e##i##_2, e##i##_3, e##i##_4;
  E5(0) E5(1) E5(2) E5(3)
#undef E5
#define STAGE(i, expr) { double td_ = (double)(expr); \
    e##i##_0 = sinf((float)td_); \
    e##i##_1 = cosf((float)(td_ * C1)); \
    e##i##_2 = sinf((float)(td_ * C2)); \
    e##i##_3 = cosf((float)(td_ * C3)); \
    e##i##_4 = sinf((float)(td_ * C4)); }
  STAGE(0, ta1[b * LEN + tid +    0])
  STAGE(1, ta1[b * LEN + tid + 1024])
  STAGE(2, ta2[b * LEN + tid +    0])
  STAGE(3, ta2[b * LEN + tid + 1024])
#undef STAGE
#define PIN5(i) asm volatile("" : "+v"(e##i##_0), "+v"(e##i##_1), \
    "+v"(e##i##_2), "+v"(e##i##_3), "+v"(e##i##_4));
  PIN5(0) PIN5(1) PIN5(2) PIN5(3)
#undef PIN5

  __syncthreads();

  for (int t = 0; t < T; t++) {
    const float4 qv = *(const float4*)&qlds[t][0];
    const float q4 = qlds[t][4];
    float Wx = 0.f, Wy = 0.f, Wz = 0.f, Ww = 0.f, W4 = 0.f, sA = 0.f, sB = 0.f;
    // scores bounded (|q.k|/sqrt8 <= 1.77): exp without max-sub, f32-safe
    // (validated absmax 0.0 across rounds 1-20)
#define EV(i, S) { \
    float s = fmaf(qv.x, e##i##_0, fmaf(qv.y, e##i##_1, \
              fmaf(qv.z, e##i##_2, fmaf(qv.w, e##i##_3, q4 * e##i##_4)))); \
    float e = __expf(s); S += e; \
    Wx = fmaf(e, e##i##_0, Wx); Wy = fmaf(e, e##i##_1, Wy); \
    Wz = fmaf(e, e##i##_2, Wz); Ww = fmaf(e, e##i##_3, Ww); \
    W4 = fmaf(e, e##i##_4, W4); }
    EV(0, sA) EV(1, sA) EV(2, sB) EV(3, sB)
#undef EV

    float r0 = wred63(Wx), r1 = wred63(Wy), r2 = wred63(Wz), r3 = wred63(Ww);
    float r4 = wred63(W4), r5 = wred63(sA), r6 = wred63(sB);
    if (lane == 63) {
      *(float4*)&strip[wave][t][0] = make_float4(r0, r1, r2, r3);
      strip[wave][t][4] = r4; strip[wave][t][5] = r5; strip[wave][t][6] = r6;
    }
  }
  __syncthreads();

  if (tid < T) {
    float f0 = 0.f, f1 = 0.f, f2 = 0.f, f3 = 0.f, f4 = 0.f, f5 = 0.f, f6 = 0.f;
#pragma unroll
    for (int w = 0; w < 16; w++) {
      float4 a = *(float4*)&strip[w][tid][0];
      float4 bq = *(float4*)&strip[w][tid][4];
      f0 += a.x; f1 += a.y; f2 += a.z; f3 += a.w;
      f4 += bq.x; f5 += bq.y; f6 += bq.z;
    }
    float inv = 1.0f / (f5 + f6);
    float* o8 = &att[(size_t)b * (T * 8) + (size_t)tid * 8];
    o8[0] = f0 * inv; o8[1] = f1 * inv; o8[2] = f2 * inv;
    o8[3] = f3 * inv; o8[4] = f4 * inv;
    o8[5] = 0.f; o8[6] = f5 * inv; o8[7] = f6 * inv;
  }
}

// ---------------- Phase B: LSTM -- unchanged from round 20 (434us) ----------------
#define XE(tb, b, e) (((tb) * BPW + (b)) * 160 + (e))

__global__ __attribute__((amdgpu_flat_work_group_size(512, 512), amdgpu_waves_per_eu(2, 4)))
void lstm_k(const float* __restrict__ att,
            const float* __restrict__ u,
            const float* __restrict__ Wih,
            const float* __restrict__ Whh,
            const float* __restrict__ bih,
            const float* __restrict__ bhh,
            const float* __restrict__ w1g,
            const float* __restrict__ b1g,
            const float* __restrict__ w2g,
            const float* __restrict__ b2g,
            float* __restrict__ out) {
  const int tid = threadIdx.x;
  const int bg = blockIdx.x * BPW;
  const int q = tid >> 2, s = tid & 3;       // P1 role: channel, 40-col segment
  const int s10 = s * 10;

  __shared__ float4 xls4[2][BPW][40];        // dbuf [x(21)|pad|hx(128)|pad(8)] per batch
  __shared__ float4 glds[BPW][128];          // gate exchange: (batch, channel) -> {i,f,g,o}
  __shared__ float tembT[101][5];            // temb(k*0.1) table
  __shared__ float uT[BPW][100];             // staged uniforms
  float* xf = (float*)xls4;

  // weight fetch (padded col coords)
#define LOADW(g, c, dstv) { \
    int E_ = 40 * s + 4 * (c); \
    if (E_ >= 24 && E_ < 152) { \
      dstv = *(const float4*)(Whh + (size_t)(q + 128 * (g)) * HID + (E_ - 24)); \
    } else if (E_ < 24) { \
      dstv.x = (E_ + 0 < 21) ? Wih[(q + 128 * (g)) * 21 + E_ + 0] : 0.f; \
      dstv.y = (E_ + 1 < 21) ? Wih[(q + 128 * (g)) * 21 + E_ + 1] : 0.f; \
      dstv.z = (E_ + 2 < 21) ? Wih[(q + 128 * (g)) * 21 + E_ + 2] : 0.f; \
      dstv.w = (E_ + 3 < 21) ? Wih[(q + 128 * (g)) * 21 + E_ + 3] : 0.f; \
    } else { dstv = make_float4(0.f, 0.f, 0.f, 0.f); } }

  // ---- one-time: 40 float4 -> 160 scalar AGPRs (r14 pattern) ----
#define DECL4(g, c) float agw##g##_##c##_0, agw##g##_##c##_1, agw##g##_##c##_2, agw##g##_##c##_3;
  DECL4(0,0) DECL4(0,1) DECL4(0,2) DECL4(0,3) DECL4(0,4) DECL4(0,5) DECL4(0,6) DECL4(0,7) DECL4(0,8) DECL4(0,9)
  DECL4(1,0) DECL4(1,1) DECL4(1,2) DECL4(1,3) DECL4(1,4) DECL4(1,5) DECL4(1,6) DECL4(1,7) DECL4(1,8) DECL4(1,9)
  DECL4(2,0) DECL4(2,1) DECL4(2,2) DECL4(2,3) DECL4(2,4) DECL4(2,5) DECL4(2,6) DECL4(2,7) DECL4(2,8) DECL4(2,9)
  DECL4(3,0) DECL4(3,1) DECL4(3,2) DECL4(3,3) DECL4(3,4) DECL4(3,5) DECL4(3,6) DECL4(3,7) DECL4(3,8) DECL4(3,9)
#undef DECL4
#define LD4(g, c) { float4 wv4_; LOADW(g, c, wv4_); \
    AGSTASH(agw##g##_##c##_0, wv4_.x); AGSTASH(agw##g##_##c##_1, wv4_.y); \
    AGSTASH(agw##g##_##c##_2, wv4_.z); AGSTASH(agw##g##_##c##_3, wv4_.w); }
  LD4(0,0) LD4(0,1) LD4(0,2) LD4(0,3) LD4(0,4) LD4(0,5) LD4(0,6) LD4(0,7) LD4(0,8) LD4(0,9)
  LD4(1,0) LD4(1,1) LD4(1,2) LD4(1,3) LD4(1,4) LD4(1,5) LD4(1,6) LD4(1,7) LD4(1,8) LD4(1,9)
  LD4(2,0) LD4(2,1) LD4(2,2) LD4(2,3) LD4(2,4) LD4(2,5) LD4(2,6) LD4(2,7) LD4(2,8) LD4(2,9)
  LD4(3,0) LD4(3,1) LD4(3,2) LD4(3,3) LD4(3,4) LD4(3,5) LD4(3,6) LD4(3,7) LD4(3,8) LD4(3,9)
#undef LD4

  // cell-role constants (P2: wave w<4 = batch w; lane l owns ch l and l+64)
  const int cA = (tid & 63), cB = cA + 64;
  float bA0 = bih[cA] + bhh[cA],             bB0 = bih[cB] + bhh[cB];
  float bA1 = bih[cA + 128] + bhh[cA + 128], bB1 = bih[cB + 128] + bhh[cB + 128];
  float bA2 = bih[cA + 256] + bhh[cA + 256], bB2 = bih[cB + 256] + bhh[cB + 256];
  float bA3 = bih[cA + 384] + bhh[cA + 384], bB3 = bih[cB + 384] + bhh[cB + 384];
  float wvA = 0.f, wvB = 0.f;
#pragma unroll
  for (int j = 0; j < 5; j++) {
    wvA = fmaf(w2g[j], w1g[j * HID + cA], wvA);
    wvB = fmaf(w2g[j], w1g[j * HID + cB], wvB);
  }
  float hconst = b2g[0];
#pragma unroll
  for (int j = 0; j < 5; j++) hconst = fmaf(w2g[j], b1g[j], hconst);
  float cxA = 0.f, cxB = 0.f;
  int lastp = 0, hasp = 0, dynp = 0;         // event state in registers (wave=batch)

  // init: zero x buffers, temb table, stage u
  for (int i = tid; i < 2 * BPW * 160; i += 512) xf[i] = 0.f;
  if (tid < 101) {
    double td = (double)tid * 0.1;
    TEMB(td);
    tembT[tid][0] = d0; tembT[tid][1] = d1; tembT[tid][2] = d2;
    tembT[tid][3] = d3; tembT[tid][4] = d4;
  }
  for (int i = tid; i < BPW * 100; i += 512) {
    int b = i / 100, tt = i - b * 100;
    uT[b][tt] = u[(size_t)(bg + b) * T + tt];
  }
  __syncthreads();

  // x(t=0): att + ct_emb(0.1)=tembT[1]; m_emb stays 0 (no event yet)
  if (tid < BPW * 8) {
    int b = tid >> 3, j = tid & 7;
    xf[XE(0, b, j)] = att[(size_t)(bg + b) * (T * 8) + j];
  } else if (tid >= 64 && tid < 64 + BPW * 5) {
    int s2 = tid - 64, b = s2 / 5, j = s2 % 5;
    xf[XE(0, b, 16 + j)] = tembT[1][j];
  }
  __syncthreads();

#define GFMA(g, c) { \
    float t0_, t1_, t2_, t3_; \
    AGREAD(t0_, agw##g##_##c##_0); AGREAD(t1_, agw##g##_##c##_1); \
    AGREAD(t2_, agw##g##_##c##_2); AGREAD(t3_, agw##g##_##c##_3); \
    v2f wlo_ = mkv2(t0_, t1_), whi_ = mkv2(t2_, t3_); \
    a##g##0 = __builtin_elementwise_fma(wlo_, x0lo, a##g##0); \
    a##g##0 = __builtin_elementwise_fma(whi_, x0hi, a##g##0); \
    a##g##1 = __builtin_elementwise_fma(wlo_, x1lo, a##g##1); \
    a##g##1 = __builtin_elementwise_fma(whi_, x1hi, a##g##1); \
    a##g##2 = __builtin_elementwise_fma(wlo_, x2lo, a##g##2); \
    a##g##2 = __builtin_elementwise_fma(whi_, x2hi, a##g##2); \
    a##g##3 = __builtin_elementwise_fma(wlo_, x3lo, a##g##3); \
    a##g##3 = __builtin_elementwise_fma(whi_, x3hi, a##g##3); }

#define CH(c) { \
    float4 xb0_ = xls4[tb][0][s10 + (c)], xb1_ = xls4[tb][1][s10 + (c)], \
           xb2_ = xls4[tb][2][s10 + (c)], xb3_ = xls4[tb][3][s10 + (c)]; \
    v2f x0lo = mkv2(xb0_.x, xb0_.y), x0hi = mkv2(xb0_.z, xb0_.w); \
    v2f x1lo = mkv2(xb1_.x, xb1_.y), x1hi = mkv2(xb1_.z, xb1_.w); \
    v2f x2lo = mkv2(xb2_.x, xb2_.y), x2hi = mkv2(xb2_.z, xb2_.w); \
    v2f x3lo = mkv2(xb3_.x, xb3_.y), x3hi = mkv2(xb3_.z, xb3_.w); \
    GFMA(0, c) GFMA(1, c) GFMA(2, c) GFMA(3, c) }

  for (int t = 0; t < T; t++) {
    const int tb = t & 1, tb1 = tb ^ 1;

    // ---- P1: pk-FMA over this thread's 40-col segment (weights from AGPR) ----
    v2f z2 = mkv2(0.f, 0.f);
    v2f a00 = z2, a01 = z2, a02 = z2, a03 = z2,
        a10 = z2, a11 = z2, a12 = z2, a13 = z2,
        a20 = z2, a21 = z2, a22 = z2, a23 = z2,
        a30 = z2, a31 = z2, a32 = z2, a33 = z2;
    CH(0) CH(1) CH(2) CH(3) CH(4) CH(5) CH(6) CH(7) CH(8) CH(9)

    float h00 = a00.x + a00.y, h01 = a01.x + a01.y, h02 = a02.x + a02.y, h03 = a03.x + a03.y;
    float h10 = a10.x + a10.y, h11 = a11.x + a11.y, h12 = a12.x + a12.y, h13 = a13.x + a13.y;
    float h20 = a20.x + a20.y, h21 = a21.x + a21.y, h22 = a22.x + a22.y, h23 = a23.x + a23.y;
    float h30 = a30.x + a30.y, h31 = a31.x + a31.y, h32 = a32.x + a32.y, h33 = a33.x + a33.y;
    RED4(h00) RED4(h01) RED4(h02) RED4(h03)
    RED4(h10) RED4(h11) RED4(h12) RED4(h13)
    RED4(h20) RED4(h21) RED4(h22) RED4(h23)
    RED4(h30) RED4(h31) RED4(h32) RED4(h33)
    if (s == 0) {   // quad lane 0 holds all 4 gates x 4 batches for channel q
      glds[0][q] = make_float4(h00, h10, h20, h30);
      glds[1][q] = make_float4(h01, h11, h21, h31);
      glds[2][q] = make_float4(h02, h12, h22, h32);
      glds[3][q] = make_float4(h03, h13, h23, h33);
    }
    __syncthreads();

    // ---- P2: wave w (<4) = batch w: cell x2ch + intra-wave head + event +
    //      x(t+1) build; waves 4-7 prefetch the att slice of x(t+1) ----
    if (tid < 256) {
      const int w = tid >> 6, l = tid & 63;
      float4 gA = glds[w][cA], gB = glds[w][cB];   // lane-consecutive: no conflicts
      cxA = sig(gA.y + bA1) * cxA + sig(gA.x + bA0) * tanhf(gA.z + bA2);
      float hnA = sig(gA.w + bA3) * tanhf(cxA);
      cxB = sig(gB.y + bB1) * cxB + sig(gB.x + bB0) * tanhf(gB.z + bB2);
      float hnB = sig(gB.w + bB3) * tanhf(cxB);
      xf[XE(tb1, w, 24 + cA)] = hnA;
      xf[XE(tb1, w, 24 + cB)] = hnB;
      float pb = wredall(fmaf(wvA, hnA, wvB * hnB));   // all lanes valid
      float hz = 1.f / (1.f + expf(-(hconst + pb)));
      int ev = (uT[w][t] < hz) ? 1 : 0;
      lastp = ev ? (t + 1) : lastp;
      hasp |= ev;
      dynp = ev ? 0 : (dynp + 1);
      if (l == 0) out[(size_t)t * BTOT + bg + w] = hz;
      if (l == 1) out[(size_t)T * BTOT + (size_t)t * BTOT + bg + w] = ev ? 1.f : 0.f;
      if (t < T - 1) {
        if (l < 5)        xf[XE(tb1, w, 8 + l)] = hasp ? tembT[lastp][l] : 0.f;
        else if (l < 8)   xf[XE(tb1, w, 13 + (l - 5))] = (l == 5 && hasp) ? 1.f : 0.f;
        else if (l < 13)  xf[XE(tb1, w, 16 + (l - 8))] = tembT[dynp + 1][l - 8];
      }
    } else if (tid < 256 + BPW * 8 && t < T - 1) {
      int s2 = tid - 256, b = s2 >> 3, j = s2 & 7;
      xf[XE(tb1, b, j)] = att[(size_t)(bg + b) * (T * 8) + (size_t)(t + 1) * 8 + j];
    }
    __syncthreads();
  }
#undef CH
#undef GFMA
#undef LOADW
}

extern "C" void kernel_launch(void* const* d_in, const int* in_sizes, int n_in,
                              void* d_out, int out_size, void* d_ws, size_t ws_size,
                              hipStream_t stream) {
  const float* ta1 = (const float*)d_in[0];
  const float* ta2 = (const float*)d_in[1];
  const float* u   = (const float*)d_in[2];
  const float* Wih = (const float*)d_in[3];
  const float* Whh = (const float*)d_in[4];
  const float* bih = (const float*)d_in[5];
  const float* bhh = (const float*)d_in[6];
  const float* w1  = (const float*)d_in[7];
  const float* b1  = (const float*)d_in[8];
  const float* w2  = (const float*)d_in[9];
  const float* b2  = (const float*)d_in[10];
  float* out = (float*)d_out;
  float* att = (float*)d_ws;   // 1024*100*8 floats = 3.28 MB scratch

  attn_k<<<dim3(BTOT), dim3(1024), 0, stream>>>(ta1, ta2, att);
  lstm_k<<<dim3(BTOT / BPW), dim3(512), 0, stream>>>(att, u, Wih, Whh, bih, bhh,
                                                     w1, b1, w2, b2, out);
}

// Round 22
// 680.201 us; speedup vs baseline: 1.1860x; 1.1860x over previous
//
#include <hip/hip_runtime.h>
#include <math.h>

#define BTOT 1024
#define LEN  2048
#define T    100
#define HID  128
#define BPW  4

// time-embedding dim constants (f64 argument scaling, f32 sincos)
#define C1 0.025118864315095794
#define C2 6.309573444801933e-04
#define C3 1.5848931924611134e-05
#define C4 3.9810717055349735e-07

#define TEMB(td) \
  float d0 = sinf((float)(td)); \
  float d1 = cosf((float)((td) * C1)); \
  float d2 = sinf((float)((td) * C2)); \
  float d3 = cosf((float)((td) * C3)); \
  float d4 = sinf((float)((td) * C4));

__device__ __forceinline__ float sig(float x) { return 1.0f / (1.0f + expf(-x)); }

using v2f = __attribute__((ext_vector_type(2))) float;
__device__ __forceinline__ v2f mkv2(float a, float b) { v2f r; r.x = a; r.y = b; return r; }

template <int CTRL>
__device__ __forceinline__ float dppadd(float x) {
  int r = __builtin_amdgcn_update_dpp(0, __float_as_int(x), CTRL, 0xF, 0xF, false);
  return x + __int_as_float(r);
}
// ROUND-22: 5-step half-wave reduction. After xor1/xor2/ror4/ror8 every lane
// of row r holds row-sum Sr (validated r6-r21); BCAST15 adds S0 into row 1
// and S2 into row 3 -> lane 31 = S0+S1, lane 63 = S2+S3. Two partials per
// wave stored (same-bank 2-lane store = free). Saves one DPP step per value
// vs r20's wred63 (attn is VALU-issue-bound on exactly this fixed overhead:
// r21 showed cost scales with THREADS, not events -> reduction dominates).
__device__ __forceinline__ float wred5(float x) {
  x = dppadd<0xB1>(x);    // quad_perm xor1
  x = dppadd<0x4E>(x);    // quad_perm xor2
  x = dppadd<0x124>(x);   // row_ror:4
  x = dppadd<0x128>(x);   // row_ror:8   -> row sums
  x = dppadd<0x142>(x);   // ROW_BCAST15 -> lane31 = S0+S1, lane63 = S2+S3
  return x;
}
// full 64-lane sum, ALL lanes valid (validated round 20).
__device__ __forceinline__ float wredall(float x) {
  x = dppadd<0xB1>(x);
  x = dppadd<0x4E>(x);
  x = dppadd<0x141>(x);
  x = dppadd<0x128>(x);
  x += __shfl_xor(x, 16);
  x += __shfl_xor(x, 32);
  return x;
}
// 4-lane quad sum (quad_perm only).
#define RED4(x) { x = dppadd<0xB1>(x); x = dppadd<0x4E>(x); }

// AGPR stash/read (validated r14). r18 lesson: VOP3P cannot read AGPRs on
// gfx950 -- weights round-trip through v_accvgpr_read.
#define AGSTASH(a_, v_) asm volatile("v_accvgpr_write_b32 %0, %1" : "=a"(a_) : "v"(v_))
#define AGREAD(v_, a_)  asm volatile("v_accvgpr_read_b32 %0, %1" : "=v"(v_) : "a"(a_))

// ---------------- Phase A: attention -- r20 shape + 5-step red + t-unroll 2 ----------------
__global__ __attribute__((amdgpu_flat_work_group_size(512, 512)))
void attn_k(const float* __restrict__ ta1,
            const float* __restrict__ ta2,
            float* __restrict__ att) {
  const int b = blockIdx.x, tid = threadIdx.x;
  const int wave = tid >> 6, lane = tid & 63;

  __shared__ float qlds[T][8];
  __shared__ float strip[16][T][8];   // two half-wave partials per wave

  if (tid < T) {
    double ct = (double)(tid + 1) * 0.1;
    TEMB(ct);
    qlds[tid][0] = d0 * 0.35355339059327373f;  // fold 1/sqrt(8)
    qlds[tid][1] = d1 * 0.35355339059327373f;
    qlds[tid][2] = d2 * 0.35355339059327373f;
    qlds[tid][3] = d3 * 0.35355339059327373f;
    qlds[tid][4] = d4 * 0.35355339059327373f;
  }

#define E5(i) float e##i##_0, e##i##_1, e##i##_2, e##i##_3, e##i##_4;
  E5(0) E5(1) E5(2) E5(3) E5(4) E5(5) E5(6) E5(7)
#undef E5
#define STAGE(i, expr) { double td_ = (double)(expr); \
    e##i##_0 = sinf((float)td_); \
    e##i##_1 = cosf((float)(td_ * C1)); \
    e##i##_2 = sinf((float)(td_ * C2)); \
    e##i##_3 = cosf((float)(td_ * C3)); \
    e##i##_4 = sinf((float)(td_ * C4)); }
  STAGE(0, ta1[b * LEN + tid +    0])
  STAGE(1, ta1[b * LEN + tid +  512])
  STAGE(2, ta1[b * LEN + tid + 1024])
  STAGE(3, ta1[b * LEN + tid + 1536])
  STAGE(4, ta2[b * LEN + tid +    0])
  STAGE(5, ta2[b * LEN + tid +  512])
  STAGE(6, ta2[b * LEN + tid + 1024])
  STAGE(7, ta2[b * LEN + tid + 1536])
#undef STAGE
#define PIN5(i) asm volatile("" : "+v"(e##i##_0), "+v"(e##i##_1), \
    "+v"(e##i##_2), "+v"(e##i##_3), "+v"(e##i##_4));
  PIN5(0) PIN5(1) PIN5(2) PIN5(3) PIN5(4) PIN5(5) PIN5(6) PIN5(7)
#undef PIN5

  __syncthreads();

  // body for one t: computes partials and stores half-wave sums
#define TBODY(t) { \
    const float4 qv = *(const float4*)&qlds[t][0]; \
    const float q4 = qlds[t][4]; \
    float Wx = 0.f, Wy = 0.f, Wz = 0.f, Ww = 0.f, W4 = 0.f, sA = 0.f, sB = 0.f; \
    EV(0, sA) EV(1, sA) EV(2, sA) EV(3, sA) \
    EV(4, sB) EV(5, sB) EV(6, sB) EV(7, sB) \
    float r0 = wred5(Wx), r1 = wred5(Wy), r2 = wred5(Wz), r3 = wred5(Ww); \
    float r4 = wred5(W4), r5 = wred5(sA), r6 = wred5(sB); \
    if ((lane & 31) == 31) { \
      int st = wave * 2 + (lane >> 5); \
      *(float4*)&strip[st][t][0] = make_float4(r0, r1, r2, r3); \
      strip[st][t][4] = r4; strip[st][t][5] = r5; strip[st][t][6] = r6; \
    } }

    // scores bounded (|q.k|/sqrt8 <= 1.77): exp without max-sub, f32-safe
    // (validated absmax 0.0 across rounds 1-21)
#define EV(i, S) { \
    float s = fmaf(qv.x, e##i##_0, fmaf(qv.y, e##i##_1, \
              fmaf(qv.z, e##i##_2, fmaf(qv.w, e##i##_3, q4 * e##i##_4)))); \
    float e = __expf(s); S += e; \
    Wx = fmaf(e, e##i##_0, Wx); Wy = fmaf(e, e##i##_1, Wy); \
    Wz = fmaf(e, e##i##_2, Wz); Ww = fmaf(e, e##i##_3, Ww); \
    W4 = fmaf(e, e##i##_4, W4); }

  for (int t = 0; t < T; t += 2) {   // T=100 even: unroll 2 shares overhead
    TBODY(t)
    TBODY(t + 1)
  }
#undef EV
#undef TBODY

  __syncthreads();

  if (tid < T) {
    float f0 = 0.f, f1 = 0.f, f2 = 0.f, f3 = 0.f, f4 = 0.f, f5 = 0.f, f6 = 0.f;
#pragma unroll
    for (int w = 0; w < 16; w++) {
      float4 a = *(float4*)&strip[w][tid][0];
      float4 bq = *(float4*)&strip[w][tid][4];
      f0 += a.x; f1 += a.y; f2 += a.z; f3 += a.w;
      f4 += bq.x; f5 += bq.y; f6 += bq.z;
    }
    float inv = 1.0f / (f5 + f6);
    float* o8 = &att[(size_t)b * (T * 8) + (size_t)tid * 8];
    o8[0] = f0 * inv; o8[1] = f1 * inv; o8[2] = f2 * inv;
    o8[3] = f3 * inv; o8[4] = f4 * inv;
    o8[5] = 0.f; o8[6] = f5 * inv; o8[7] = f6 * inv;
  }
}

// ---------------- Phase B: LSTM -- unchanged from round 20 (434us best) ----------------
#define XE(tb, b, e) (((tb) * BPW + (b)) * 160 + (e))

__global__ __attribute__((amdgpu_flat_work_group_size(512, 512), amdgpu_waves_per_eu(2, 4)))
void lstm_k(const float* __restrict__ att,
            const float* __restrict__ u,
            const float* __restrict__ Wih,
            const float* __restrict__ Whh,
            const float* __restrict__ bih,
            const float* __restrict__ bhh,
            const float* __restrict__ w1g,
            const float* __restrict__ b1g,
            const float* __restrict__ w2g,
            const float* __restrict__ b2g,
            float* __restrict__ out) {
  const int tid = threadIdx.x;
  const int bg = blockIdx.x * BPW;
  const int q = tid >> 2, s = tid & 3;       // P1 role: channel, 40-col segment
  const int s10 = s * 10;

  __shared__ float4 xls4[2][BPW][40];        // dbuf [x(21)|pad|hx(128)|pad(8)] per batch
  __shared__ float4 glds[BPW][128];          // gate exchange: (batch, channel) -> {i,f,g,o}
  __shared__ float tembT[101][5];            // temb(k*0.1) table
  __shared__ float uT[BPW][100];             // staged uniforms
  float* xf = (float*)xls4;

  // weight fetch (padded col coords)
#define LOADW(g, c, dstv) { \
    int E_ = 40 * s + 4 * (c); \
    if (E_ >= 24 && E_ < 152) { \
      dstv = *(const float4*)(Whh + (size_t)(q + 128 * (g)) * HID + (E_ - 24)); \
    } else if (E_ < 24) { \
      dstv.x = (E_ + 0 < 21) ? Wih[(q + 128 * (g)) * 21 + E_ + 0] : 0.f; \
      dstv.y = (E_ + 1 < 21) ? Wih[(q + 128 * (g)) * 21 + E_ + 1] : 0.f; \
      dstv.z = (E_ + 2 < 21) ? Wih[(q + 128 * (g)) * 21 + E_ + 2] : 0.f; \
      dstv.w = (E_ + 3 < 21) ? Wih[(q + 128 * (g)) * 21 + E_ + 3] : 0.f; \
    } else { dstv = make_float4(0.f, 0.f, 0.f, 0.f); } }

  // ---- one-time: 40 float4 -> 160 scalar AGPRs (r14 pattern) ----
#define DECL4(g, c) float agw##g##_##c##_0, agw##g##_##c##_1, agw##g##_##c##_2, agw##g##_##c##_3;
  DECL4(0,0) DECL4(0,1) DECL4(0,2) DECL4(0,3) DECL4(0,4) DECL4(0,5) DECL4(0,6) DECL4(0,7) DECL4(0,8) DECL4(0,9)
  DECL4(1,0) DECL4(1,1) DECL4(1,2) DECL4(1,3) DECL4(1,4) DECL4(1,5) DECL4(1,6) DECL4(1,7) DECL4(1,8) DECL4(1,9)
  DECL4(2,0) DECL4(2,1) DECL4(2,2) DECL4(2,3) DECL4(2,4) DECL4(2,5) DECL4(2,6) DECL4(2,7) DECL4(2,8) DECL4(2,9)
  DECL4(3,0) DECL4(3,1) DECL4(3,2) DECL4(3,3) DECL4(3,4) DECL4(3,5) DECL4(3,6) DECL4(3,7) DECL4(3,8) DECL4(3,9)
#undef DECL4
#define LD4(g, c) { float4 wv4_; LOADW(g, c, wv4_); \
    AGSTASH(agw##g##_##c##_0, wv4_.x); AGSTASH(agw##g##_##c##_1, wv4_.y); \
    AGSTASH(agw##g##_##c##_2, wv4_.z); AGSTASH(agw##g##_##c##_3, wv4_.w); }
  LD4(0,0) LD4(0,1) LD4(0,2) LD4(0,3) LD4(0,4) LD4(0,5) LD4(0,6) LD4(0,7) LD4(0,8) LD4(0,9)
  LD4(1,0) LD4(1,1) LD4(1,2) LD4(1,3) LD4(1,4) LD4(1,5) LD4(1,6) LD4(1,7) LD4(1,8) LD4(1,9)
  LD4(2,0) LD4(2,1) LD4(2,2) LD4(2,3) LD4(2,4) LD4(2,5) LD4(2,6) LD4(2,7) LD4(2,8) LD4(2,9)
  LD4(3,0) LD4(3,1) LD4(3,2) LD4(3,3) LD4(3,4) LD4(3,5) LD4(3,6) LD4(3,7) LD4(3,8) LD4(3,9)
#undef LD4

  // cell-role constants (P2: wave w<4 = batch w; lane l owns ch l and l+64)
  const int cA = (tid & 63), cB = cA + 64;
  float bA0 = bih[cA] + bhh[cA],             bB0 = bih[cB] + bhh[cB];
  float bA1 = bih[cA + 128] + bhh[cA + 128], bB1 = bih[cB + 128] + bhh[cB + 128];
  float bA2 = bih[cA + 256] + bhh[cA + 256], bB2 = bih[cB + 256] + bhh[cB + 256];
  float bA3 = bih[cA + 384] + bhh[cA + 384], bB3 = bih[cB + 384] + bhh[cB + 384];
  float wvA = 0.f, wvB = 0.f;
#pragma unroll
  for (int j = 0; j < 5; j++) {
    wvA = fmaf(w2g[j], w1g[j * HID + cA], wvA);
    wvB = fmaf(w2g[j], w1g[j * HID + cB], wvB);
  }
  float hconst = b2g[0];
#pragma unroll
  for (int j = 0; j < 5; j++) hconst = fmaf(w2g[j], b1g[j], hconst);
  float cxA = 0.f, cxB = 0.f;
  int lastp = 0, hasp = 0, dynp = 0;         // event state in registers (wave=batch)

  // init: zero x buffers, temb table, stage u
  for (int i = tid; i < 2 * BPW * 160; i += 512) xf[i] = 0.f;
  if (tid < 101) {
    double td = (double)tid * 0.1;
    TEMB(td);
    tembT[tid][0] = d0; tembT[tid][1] = d1; tembT[tid][2] = d2;
    tembT[tid][3] = d3; tembT[tid][4] = d4;
  }
  for (int i = tid; i < BPW * 100; i += 512) {
    int b = i / 100, tt = i - b * 100;
    uT[b][tt] = u[(size_t)(bg + b) * T + tt];
  }
  __syncthreads();

  // x(t=0): att + ct_emb(0.1)=tembT[1]; m_emb stays 0 (no event yet)
  if (tid < BPW * 8) {
    int b = tid >> 3, j = tid & 7;
    xf[XE(0, b, j)] = att[(size_t)(bg + b) * (T * 8) + j];
  } else if (tid >= 64 && tid < 64 + BPW * 5) {
    int s2 = tid - 64, b = s2 / 5, j = s2 % 5;
    xf[XE(0, b, 16 + j)] = tembT[1][j];
  }
  __syncthreads();

#define GFMA(g, c) { \
    float t0_, t1_, t2_, t3_; \
    AGREAD(t0_, agw##g##_##c##_0); AGREAD(t1_, agw##g##_##c##_1); \
    AGREAD(t2_, agw##g##_##c##_2); AGREAD(t3_, agw##g##_##c##_3); \
    v2f wlo_ = mkv2(t0_, t1_), whi_ = mkv2(t2_, t3_); \
    a##g##0 = __builtin_elementwise_fma(wlo_, x0lo, a##g##0); \
    a##g##0 = __builtin_elementwise_fma(whi_, x0hi, a##g##0); \
    a##g##1 = __builtin_elementwise_fma(wlo_, x1lo, a##g##1); \
    a##g##1 = __builtin_elementwise_fma(whi_, x1hi, a##g##1); \
    a##g##2 = __builtin_elementwise_fma(wlo_, x2lo, a##g##2); \
    a##g##2 = __builtin_elementwise_fma(whi_, x2hi, a##g##2); \
    a##g##3 = __builtin_elementwise_fma(wlo_, x3lo, a##g##3); \
    a##g##3 = __builtin_elementwise_fma(whi_, x3hi, a##g##3); }

#define CH(c) { \
    float4 xb0_ = xls4[tb][0][s10 + (c)], xb1_ = xls4[tb][1][s10 + (c)], \
           xb2_ = xls4[tb][2][s10 + (c)], xb3_ = xls4[tb][3][s10 + (c)]; \
    v2f x0lo = mkv2(xb0_.x, xb0_.y), x0hi = mkv2(xb0_.z, xb0_.w); \
    v2f x1lo = mkv2(xb1_.x, xb1_.y), x1hi = mkv2(xb1_.z, xb1_.w); \
    v2f x2lo = mkv2(xb2_.x, xb2_.y), x2hi = mkv2(xb2_.z, xb2_.w); \
    v2f x3lo = mkv2(xb3_.x, xb3_.y), x3hi = mkv2(xb3_.z, xb3_.w); \
    GFMA(0, c) GFMA(1, c) GFMA(2, c) GFMA(3, c) }

  for (int t = 0; t < T; t++) {
    const int tb = t & 1, tb1 = tb ^ 1;

    // ---- P1: pk-FMA over this thread's 40-col segment (weights from AGPR) ----
    v2f z2 = mkv2(0.f, 0.f);
    v2f a00 = z2, a01 = z2, a02 = z2, a03 = z2,
        a10 = z2, a11 = z2, a12 = z2, a13 = z2,
        a20 = z2, a21 = z2, a22 = z2, a23 = z2,
        a30 = z2, a31 = z2, a32 = z2, a33 = z2;
    CH(0) CH(1) CH(2) CH(3) CH(4) CH(5) CH(6) CH(7) CH(8) CH(9)

    float h00 = a00.x + a00.y, h01 = a01.x + a01.y, h02 = a02.x + a02.y, h03 = a03.x + a03.y;
    float h10 = a10.x + a10.y, h11 = a11.x + a11.y, h12 = a12.x + a12.y, h13 = a13.x + a13.y;
    float h20 = a20.x + a20.y, h21 = a21.x + a21.y, h22 = a22.x + a22.y, h23 = a23.x + a23.y;
    float h30 = a30.x + a30.y, h31 = a31.x + a31.y, h32 = a32.x + a32.y, h33 = a33.x + a33.y;
    RED4(h00) RED4(h01) RED4(h02) RED4(h03)
    RED4(h10) RED4(h11) RED4(h12) RED4(h13)
    RED4(h20) RED4(h21) RED4(h22) RED4(h23)
    RED4(h30) RED4(h31) RED4(h32) RED4(h33)
    if (s == 0) {   // quad lane 0 holds all 4 gates x 4 batches for channel q
      glds[0][q] = make_float4(h00, h10, h20, h30);
      glds[1][q] = make_float4(h01, h11, h21, h31);
      glds[2][q] = make_float4(h02, h12, h22, h32);
      glds[3][q] = make_float4(h03, h13, h23, h33);
    }
    __syncthreads();

    // ---- P2: wave w (<4) = batch w: cell x2ch + intra-wave head + event +
    //      x(t+1) build; waves 4-7 prefetch the att slice of x(t+1) ----
    if (tid < 256) {
      const int w = tid >> 6, l = tid & 63;
      float4 gA = glds[w][cA], gB = glds[w][cB];   // lane-consecutive: no conflicts
      cxA = sig(gA.y + bA1) * cxA + sig(gA.x + bA0) * tanhf(gA.z + bA2);
      float hnA = sig(gA.w + bA3) * tanhf(cxA);
      cxB = sig(gB.y + bB1) * cxB + sig(gB.x + bB0) * tanhf(gB.z + bB2);
      float hnB = sig(gB.w + bB3) * tanhf(cxB);
      xf[XE(tb1, w, 24 + cA)] = hnA;
      xf[XE(tb1, w, 24 + cB)] = hnB;
      float pb = wredall(fmaf(wvA, hnA, wvB * hnB));   // all lanes valid
      float hz = 1.f / (1.f + expf(-(hconst + pb)));
      int ev = (uT[w][t] < hz) ? 1 : 0;
      lastp = ev ? (t + 1) : lastp;
      hasp |= ev;
      dynp = ev ? 0 : (dynp + 1);
      if (l == 0) out[(size_t)t * BTOT + bg + w] = hz;
      if (l == 1) out[(size_t)T * BTOT + (size_t)t * BTOT + bg + w] = ev ? 1.f : 0.f;
      if (t < T - 1) {
        if (l < 5)        xf[XE(tb1, w, 8 + l)] = hasp ? tembT[lastp][l] : 0.f;
        else if (l < 8)   xf[XE(tb1, w, 13 + (l - 5))] = (l == 5 && hasp) ? 1.f : 0.f;
        else if (l < 13)  xf[XE(tb1, w, 16 + (l - 8))] = tembT[dynp + 1][l - 8];
      }
    } else if (tid < 256 + BPW * 8 && t < T - 1) {
      int s2 = tid - 256, b = s2 >> 3, j = s2 & 7;
      xf[XE(tb1, b, j)] = att[(size_t)(bg + b) * (T * 8) + (size_t)(t + 1) * 8 + j];
    }
    __syncthreads();
  }
#undef CH
#undef GFMA
#undef LOADW
}

extern "C" void kernel_launch(void* const* d_in, const int* in_sizes, int n_in,
                              void* d_out, int out_size, void* d_ws, size_t ws_size,
                              hipStream_t stream) {
  const float* ta1 = (const float*)d_in[0];
  const float* ta2 = (const float*)d_in[1];
  const float* u   = (const float*)d_in[2];
  const float* Wih = (const float*)d_in[3];
  const float* Whh = (const float*)d_in[4];
  const float* bih = (const float*)d_in[5];
  const float* bhh = (const float*)d_in[6];
  const float* w1  = (const float*)d_in[7];
  const float* b1  = (const float*)d_in[8];
  const float* w2  = (const float*)d_in[9];
  const float* b2  = (const float*)d_in[10];
  float* out = (float*)d_out;
  float* att = (float*)d_ws;   // 1024*100*8 floats = 3.28 MB scratch

  attn_k<<<dim3(BTOT), dim3(512), 0, stream>>>(ta1, ta2, att);
  lstm_k<<<dim3(BTOT / BPW), dim3(512), 0, stream>>>(att, u, Wih, Whh, bih, bhh,
                                                     w1, b1, w2, b2, out);
}